// Round 5
// baseline (113.634 us; speedup 1.0000x reference)
//
#include <hip/hip_runtime.h>
#include <math.h>

#define HDIM 128
#define WDIM 128
#define CDIM 64
#define BDIM 4
#define NPIX (BDIM * HDIM * WDIM)   // 65536

// ---------------------------------------------------------------------------
// Kernel 1 (v2): dual 1x1 conv, fp32 vector ALU, 8px x 8d micro-tile.
//   Round-4 rework: old 4px x 8d needed 3 ds_read_b128 per 32 FMA (LDS floor
//   15.4 us). New 8x8 needs 4 b128 per 64 FMA (floor 10.2 us; VALU floor
//   6.8 us). Block = 128 threads (2 waves), tile 128 px x 64 d.
//   LDS: Ws 16,384 B + xs 64x132x4 = 33,792 B -> 50,176 B -> 3 blocks/CU.
//   Transpose-scatter staging writes use an XOR swizzle (phys_px = px ^
//   8*((c>>2)&3)): 4-way write conflicts (was 8-way), compute reads stay
//   16-B aligned and <=2 addresses/bank (free).
// ---------------------------------------------------------------------------
__global__ __launch_bounds__(128, 1)
void conv1x1_kernel(const float* __restrict__ xm,
                    const float* __restrict__ xr,
                    const float* __restrict__ Wm,
                    const float* __restrict__ Wr,
                    float* __restrict__ outm,
                    float* __restrict__ outr) {
    const float* x; const float* Wg; float* out;
    if (blockIdx.y == 0) { x = xm; Wg = Wm; out = outm; }
    else                 { x = xr; Wg = Wr; out = outr; }

    __shared__ float Ws[CDIM][CDIM];   // [c][d], stride 64
    __shared__ float xs[CDIM][132];    // [c][phys_px], stride 132 (= 4 mod 32)

    const int t = threadIdx.x;          // 0..127
    const int pxbase = blockIdx.x * 128;

    // ---- stage W: 4096 floats = 1024 float4, 8 iters ----
    {
        const float4* Wg4 = (const float4*)Wg;
        float4* Ws4 = (float4*)&Ws[0][0];
        #pragma unroll
        for (int i = 0; i < 8; ++i) Ws4[t + 128 * i] = Wg4[t + 128 * i];
    }
    // ---- stage x transposed+swizzled: 128 px x 16 float4, 16 iters ----
    #pragma unroll
    for (int i = 0; i < 16; ++i) {
        int L  = t + 128 * i;
        int px = L >> 4;                 // logical pixel 0..127
        int c4 = L & 15;                 // float4 chunk of channels
        float4 v = *(const float4*)&x[(size_t)(pxbase + px) * CDIM + 4 * c4];
        int ppx = px ^ (8 * (c4 & 3));   // XOR swizzle (c>>2 == c4 for 4c4+q)
        xs[4 * c4 + 0][ppx] = v.x;
        xs[4 * c4 + 1][ppx] = v.y;
        xs[4 * c4 + 2][ppx] = v.z;
        xs[4 * c4 + 3][ppx] = v.w;
    }
    __syncthreads();

    const int dg = t & 7;    // 8 d-groups of 8 cols
    const int pg = t >> 3;   // 16 px-groups of 8 rows

    float acc[8][8];
    #pragma unroll
    for (int i = 0; i < 8; ++i)
        #pragma unroll
        for (int j = 0; j < 8; ++j) acc[i][j] = 0.f;

    #pragma unroll 16
    for (int c = 0; c < CDIM; ++c) {
        const int s = (c >> 2) & 3;                       // matches staging swizzle
        const float4* xp = (const float4*)&xs[c][8 * (pg ^ s)];
        const float4* wp = (const float4*)&Ws[c][8 * dg];
        float4 x0 = xp[0], x1 = xp[1];
        float4 w0 = wp[0], w1 = wp[1];
        float xa[8] = {x0.x, x0.y, x0.z, x0.w, x1.x, x1.y, x1.z, x1.w};
        float wa[8] = {w0.x, w0.y, w0.z, w0.w, w1.x, w1.y, w1.z, w1.w};
        #pragma unroll
        for (int i = 0; i < 8; ++i)
            #pragma unroll
            for (int j = 0; j < 8; ++j)
                acc[i][j] = fmaf(xa[i], wa[j], acc[i][j]);
    }

    #pragma unroll
    for (int i = 0; i < 8; ++i) {
        int px = pxbase + pg * 8 + i;
        float4 o0 = {acc[i][0], acc[i][1], acc[i][2], acc[i][3]};
        float4 o1 = {acc[i][4], acc[i][5], acc[i][6], acc[i][7]};
        *(float4*)&out[(size_t)px * CDIM + dg * 8]     = o0;
        *(float4*)&out[(size_t)px * CDIM + dg * 8 + 4] = o1;
    }
}

// ---------------------------------------------------------------------------
// Kernel 2 (v4, unchanged): LDS-tiled scores + softmax, scores in VGPRs.
// ---------------------------------------------------------------------------
#define TILE_W 16
#define TILE_H 8
#define HALO_W 20               // TILE_W + 4
#define HALO_H 12               // TILE_H + 4
#define NHALO (HALO_W * HALO_H) // 240
#define PSTRIDE 68              // floats per halo pixel in LDS (16-B aligned)

__global__ __launch_bounds__(256, 1)
void attn_tiled_kernel(const float* __restrict__ cm,
                       const float* __restrict__ cr,
                       float* __restrict__ out) {
    __shared__ float crs[NHALO * PSTRIDE];   // 65,280 B

    const int t   = threadIdx.x;
    const int tx0 = blockIdx.x * TILE_W;
    const int ty0 = blockIdx.y * TILE_H;
    const int b   = blockIdx.z;

    // ---- stage cr halo tile: 240 px x 16 float4 = 3840 float4, 15 iters ----
    #pragma unroll
    for (int it = 0; it < 15; ++it) {
        int L   = t + 256 * it;
        int pix = L >> 4;                   // 0..239
        int q   = L & 15;                   // float4 chunk within pixel
        int hy  = pix / HALO_W;
        int hx  = pix - hy * HALO_W;
        int gy  = ty0 + hy - 2, gx = tx0 + hx - 2;
        float4 v = make_float4(0.f, 0.f, 0.f, 0.f);
        if (gy >= 0 && gy < HDIM && gx >= 0 && gx < WDIM) {
            size_t gp = ((size_t)b * HDIM + gy) * WDIM + gx;
            v = *(const float4*)&cr[gp * CDIM + 4 * q];
        }
        *(float4*)&crs[pix * PSTRIDE + 4 * q] = v;
    }
    __syncthreads();

    // ---- per-thread: one pixel, one channel half ----
    const int pl = t >> 1;                  // local pixel 0..127
    const int cg = t & 1;                   // channel half
    const int lx = pl & (TILE_W - 1);
    const int ly = pl >> 4;                 // 0..7
    const size_t gpx = ((size_t)b * HDIM + ty0 + ly) * WDIM + tx0 + lx;

    float4 qv[8];
    {
        const float4* cmp = (const float4*)&cm[gpx * CDIM + cg * 32];
        #pragma unroll
        for (int m = 0; m < 8; ++m) qv[m] = cmp[m];
    }

    float s[26];
    #pragma unroll
    for (int k = 0; k < 25; ++k) {
        const int i = k / 5, j = k % 5;
        const int p = (ly + i) * HALO_W + (lx + j);
        const float4* kp = (const float4*)&crs[p * PSTRIDE + cg * 32];
        float acc = 0.f;
        #pragma unroll
        for (int m = 0; m < 8; ++m) {
            float4 v = kp[m];
            acc = fmaf(qv[m].x, v.x, acc);
            acc = fmaf(qv[m].y, v.y, acc);
            acc = fmaf(qv[m].z, v.z, acc);
            acc = fmaf(qv[m].w, v.w, acc);
        }
        s[k] = acc;
    }
    {
        float acc = 0.f;
        #pragma unroll
        for (int m = 0; m < 8; ++m) {
            float4 v = qv[m];
            acc = fmaf(v.x, v.x, acc);
            acc = fmaf(v.y, v.y, acc);
            acc = fmaf(v.z, v.z, acc);
            acc = fmaf(v.w, v.w, acc);
        }
        s[25] = acc;
    }

    // combine channel halves (lanes 2k/2k+1 hold same pixel)
    #pragma unroll
    for (int k = 0; k < 26; ++k) s[k] += __shfl_xor(s[k], 1);

    // softmax over 26 (both lanes compute; each writes 13)
    float mx = s[0];
    #pragma unroll
    for (int k = 1; k < 26; ++k) mx = fmaxf(mx, s[k]);
    float sum = 0.f;
    #pragma unroll
    for (int k = 0; k < 26; ++k) { s[k] = __expf(s[k] - mx); sum += s[k]; }
    const float inv = 1.f / sum;

    // ALL indices compile-time constant -> s[] stays in VGPRs.
    float* op = &out[gpx * 26 + cg * 13];
    if (cg == 0) {
        #pragma unroll
        for (int k = 0; k < 13; ++k) op[k] = s[k] * inv;
    } else {
        #pragma unroll
        for (int k = 0; k < 13; ++k) op[k] = s[13 + k] * inv;
    }
}

// ---------------------------------------------------------------------------
extern "C" void kernel_launch(void* const* d_in, const int* in_sizes, int n_in,
                              void* d_out, int out_size, void* d_ws, size_t ws_size,
                              hipStream_t stream) {
    const float* xm = (const float*)d_in[0];
    const float* xr = (const float*)d_in[1];
    const float* Wm = (const float*)d_in[2];
    const float* Wr = (const float*)d_in[3];
    float* outp = (float*)d_out;

    float* cm = (float*)d_ws;
    float* cr = cm + (size_t)NPIX * CDIM;

    dim3 g1(NPIX / 128, 2);                        // 512 x 2 blocks, 128 thr
    conv1x1_kernel<<<g1, 128, 0, stream>>>(xm, xr, Wm, Wr, cm, cr);

    dim3 g2(WDIM / TILE_W, HDIM / TILE_H, BDIM);   // 8 x 16 x 4 = 512 blocks
    attn_tiled_kernel<<<g2, 256, 0, stream>>>(cm, cr, outp);
}

// Round 6
// 107.690 us; speedup vs baseline: 1.0552x; 1.0552x over previous
//
#include <hip/hip_runtime.h>
#include <math.h>

#define HDIM 128
#define WDIM 128
#define CDIM 64
#define BDIM 4
#define NPIX (BDIM * HDIM * WDIM)   // 65536

// ---------------------------------------------------------------------------
// Kernel 1 (v3): dual 1x1 conv, fp32 vector ALU.
//   Round-5 post-mortem: v2's 8x8 micro-tile was right but 128-thr blocks +
//   50 KB LDS gave only 6 waves/CU -> latency wall. v3 keeps 8x8 AND 4
//   waves/block: tile 256 px x 64 d, 256 threads, x staged in TWO 32-channel
//   K-chunks (xs 32x260 = 33.3 KB + Ws 32x64 = 8.2 KB = 41.5 KB; grid 512
//   blocks -> 2 blocks/CU -> 8 waves/CU). Stride 260 (=4 mod 32, 16B-aligned
//   rows); XOR swizzle ppx = px ^ 8*(c4&3) makes transpose-writes 2-way max,
//   reads compensated with pg ^ s (swizzle pair correctness proven in v2).
//   Floors: LDS ~11 us, VALU 6.8 us -> expect ~12-14 us (v1 was ~25).
// ---------------------------------------------------------------------------
__global__ __launch_bounds__(256, 1)
void conv1x1_kernel(const float* __restrict__ xm,
                    const float* __restrict__ xr,
                    const float* __restrict__ Wm,
                    const float* __restrict__ Wr,
                    float* __restrict__ outm,
                    float* __restrict__ outr) {
    const float* x; const float* Wg; float* out;
    if (blockIdx.y == 0) { x = xm; Wg = Wm; out = outm; }
    else                 { x = xr; Wg = Wr; out = outr; }

    __shared__ float Ws[32][64];    // current K-chunk of W   (8,192 B)
    __shared__ float xs[32][260];   // current K-chunk of x^T (33,280 B)

    const int t = threadIdx.x;          // 0..255
    const int pxbase = blockIdx.x * 256;
    const int dg = t & 7;               // 8 d-groups of 8 cols
    const int pg = t >> 3;              // 32 px-groups of 8 rows

    float acc[8][8];
    #pragma unroll
    for (int i = 0; i < 8; ++i)
        #pragma unroll
        for (int j = 0; j < 8; ++j) acc[i][j] = 0.f;

    for (int kc = 0; kc < 2; ++kc) {
        // ---- stage W chunk: rows kc*32..+31, 2048 floats = 512 f4 ----
        {
            const float4* Wg4 = (const float4*)(Wg + kc * 32 * CDIM);
            float4* Ws4 = (float4*)&Ws[0][0];
            Ws4[t]       = Wg4[t];
            Ws4[t + 256] = Wg4[t + 256];
        }
        // ---- stage x chunk transposed+swizzled: 256 px x 8 f4, 8 iters ----
        #pragma unroll
        for (int i = 0; i < 8; ++i) {
            int L  = t + 256 * i;
            int px = L >> 3;                 // 0..255
            int c4 = L & 7;                  // f4 chunk of the 32 channels
            float4 v = *(const float4*)&x[(size_t)(pxbase + px) * CDIM
                                          + kc * 32 + 4 * c4];
            int ppx = px ^ (8 * (c4 & 3));   // XOR swizzle
            xs[4 * c4 + 0][ppx] = v.x;
            xs[4 * c4 + 1][ppx] = v.y;
            xs[4 * c4 + 2][ppx] = v.z;
            xs[4 * c4 + 3][ppx] = v.w;
        }
        __syncthreads();

        #pragma unroll 4
        for (int c = 0; c < 32; ++c) {
            const int s = (c >> 2) & 3;      // matches staging swizzle
            const float4* xp = (const float4*)&xs[c][8 * (pg ^ s)];
            const float4* wp = (const float4*)&Ws[c][8 * dg];
            float4 x0 = xp[0], x1 = xp[1];
            float4 w0 = wp[0], w1 = wp[1];
            float xa[8] = {x0.x, x0.y, x0.z, x0.w, x1.x, x1.y, x1.z, x1.w};
            float wa[8] = {w0.x, w0.y, w0.z, w0.w, w1.x, w1.y, w1.z, w1.w};
            #pragma unroll
            for (int i = 0; i < 8; ++i)
                #pragma unroll
                for (int j = 0; j < 8; ++j)
                    acc[i][j] = fmaf(xa[i], wa[j], acc[i][j]);
        }
        __syncthreads();   // protect xs/Ws before restaging next chunk
    }

    #pragma unroll
    for (int i = 0; i < 8; ++i) {
        int px = pxbase + pg * 8 + i;
        float4 o0 = {acc[i][0], acc[i][1], acc[i][2], acc[i][3]};
        float4 o1 = {acc[i][4], acc[i][5], acc[i][6], acc[i][7]};
        *(float4*)&out[(size_t)px * CDIM + dg * 8]     = o0;
        *(float4*)&out[(size_t)px * CDIM + dg * 8 + 4] = o1;
    }
}

// ---------------------------------------------------------------------------
// Kernel 2 (v4, unchanged): LDS-tiled scores + softmax, scores in VGPRs.
// ---------------------------------------------------------------------------
#define TILE_W 16
#define TILE_H 8
#define HALO_W 20               // TILE_W + 4
#define HALO_H 12               // TILE_H + 4
#define NHALO (HALO_W * HALO_H) // 240
#define PSTRIDE 68              // floats per halo pixel in LDS (16-B aligned)

__global__ __launch_bounds__(256, 1)
void attn_tiled_kernel(const float* __restrict__ cm,
                       const float* __restrict__ cr,
                       float* __restrict__ out) {
    __shared__ float crs[NHALO * PSTRIDE];   // 65,280 B

    const int t   = threadIdx.x;
    const int tx0 = blockIdx.x * TILE_W;
    const int ty0 = blockIdx.y * TILE_H;
    const int b   = blockIdx.z;

    // ---- stage cr halo tile: 240 px x 16 float4 = 3840 float4, 15 iters ----
    #pragma unroll
    for (int it = 0; it < 15; ++it) {
        int L   = t + 256 * it;
        int pix = L >> 4;                   // 0..239
        int q   = L & 15;                   // float4 chunk within pixel
        int hy  = pix / HALO_W;
        int hx  = pix - hy * HALO_W;
        int gy  = ty0 + hy - 2, gx = tx0 + hx - 2;
        float4 v = make_float4(0.f, 0.f, 0.f, 0.f);
        if (gy >= 0 && gy < HDIM && gx >= 0 && gx < WDIM) {
            size_t gp = ((size_t)b * HDIM + gy) * WDIM + gx;
            v = *(const float4*)&cr[gp * CDIM + 4 * q];
        }
        *(float4*)&crs[pix * PSTRIDE + 4 * q] = v;
    }
    __syncthreads();

    // ---- per-thread: one pixel, one channel half ----
    const int pl = t >> 1;                  // local pixel 0..127
    const int cg = t & 1;                   // channel half
    const int lx = pl & (TILE_W - 1);
    const int ly = pl >> 4;                 // 0..7
    const size_t gpx = ((size_t)b * HDIM + ty0 + ly) * WDIM + tx0 + lx;

    float4 qv[8];
    {
        const float4* cmp = (const float4*)&cm[gpx * CDIM + cg * 32];
        #pragma unroll
        for (int m = 0; m < 8; ++m) qv[m] = cmp[m];
    }

    float s[26];
    #pragma unroll
    for (int k = 0; k < 25; ++k) {
        const int i = k / 5, j = k % 5;
        const int p = (ly + i) * HALO_W + (lx + j);
        const float4* kp = (const float4*)&crs[p * PSTRIDE + cg * 32];
        float acc = 0.f;
        #pragma unroll
        for (int m = 0; m < 8; ++m) {
            float4 v = kp[m];
            acc = fmaf(qv[m].x, v.x, acc);
            acc = fmaf(qv[m].y, v.y, acc);
            acc = fmaf(qv[m].z, v.z, acc);
            acc = fmaf(qv[m].w, v.w, acc);
        }
        s[k] = acc;
    }
    {
        float acc = 0.f;
        #pragma unroll
        for (int m = 0; m < 8; ++m) {
            float4 v = qv[m];
            acc = fmaf(v.x, v.x, acc);
            acc = fmaf(v.y, v.y, acc);
            acc = fmaf(v.z, v.z, acc);
            acc = fmaf(v.w, v.w, acc);
        }
        s[25] = acc;
    }

    // combine channel halves (lanes 2k/2k+1 hold same pixel)
    #pragma unroll
    for (int k = 0; k < 26; ++k) s[k] += __shfl_xor(s[k], 1);

    // softmax over 26 (both lanes compute; each writes 13)
    float mx = s[0];
    #pragma unroll
    for (int k = 1; k < 26; ++k) mx = fmaxf(mx, s[k]);
    float sum = 0.f;
    #pragma unroll
    for (int k = 0; k < 26; ++k) { s[k] = __expf(s[k] - mx); sum += s[k]; }
    const float inv = 1.f / sum;

    // ALL indices compile-time constant -> s[] stays in VGPRs.
    float* op = &out[gpx * 26 + cg * 13];
    if (cg == 0) {
        #pragma unroll
        for (int k = 0; k < 13; ++k) op[k] = s[k] * inv;
    } else {
        #pragma unroll
        for (int k = 0; k < 13; ++k) op[k] = s[13 + k] * inv;
    }
}

// ---------------------------------------------------------------------------
extern "C" void kernel_launch(void* const* d_in, const int* in_sizes, int n_in,
                              void* d_out, int out_size, void* d_ws, size_t ws_size,
                              hipStream_t stream) {
    const float* xm = (const float*)d_in[0];
    const float* xr = (const float*)d_in[1];
    const float* Wm = (const float*)d_in[2];
    const float* Wr = (const float*)d_in[3];
    float* outp = (float*)d_out;

    float* cm = (float*)d_ws;
    float* cr = cm + (size_t)NPIX * CDIM;

    dim3 g1(NPIX / 256, 2);                        // 256 x 2 = 512 blocks
    conv1x1_kernel<<<g1, 256, 0, stream>>>(xm, xr, Wm, Wr, cm, cr);

    dim3 g2(WDIM / TILE_W, HDIM / TILE_H, BDIM);   // 8 x 16 x 4 = 512 blocks
    attn_tiled_kernel<<<g2, 256, 0, stream>>>(cm, cr, outp);
}

// Round 7
// 102.907 us; speedup vs baseline: 1.1042x; 1.0465x over previous
//
#include <hip/hip_runtime.h>
#include <math.h>

#define HDIM 128
#define WDIM 128
#define CDIM 64
#define BDIM 4
#define NPIX (BDIM * HDIM * WDIM)   // 65536

#define TILE_W 16
#define TILE_H 8
#define HALO_W 20               // TILE_W + 4
#define HALO_H 12               // TILE_H + 4
#define NHALO (HALO_W * HALO_H) // 240 real halo pixels
#define MSLOT 256               // cr GEMM M padded to 256 slots (16 dead)
#define PSTRIDE 68              // crs/cm pixel stride in LDS (16-B aligned, 4 mod 32)
#define XSTRIDE 260             // xs pixel stride (16-B aligned, 4 mod 32)

// ---------------------------------------------------------------------------
// Fused kernel: conv(x_main)->cm, conv(x_ref)->cr(halo), scores, softmax.
//   One kernel, no workspace. LDS (65,280 B) is time-multiplexed:
//     phases 1-2 (GEMMs):  Wsh[32][64] @ lds[0..2048) + xsh[32][260] @ [2048..10368)
//     phase 3 (qv xchg):   cm[128][68] @ lds[0..8704)
//     phases 4-5 (scores): crs[240][68] @ lds[0..16320)
//   cm held in 32 regs, cr in 64 regs across phases (all indices compile-time
//   -> no scratch; round-3 lesson). XOR swizzle ppx = px ^ 8*(c4&3) on xs
//   staging, compensated at read with pxgrp ^ 8*s — proven in conv v2/v3.
//   cr halo recompute factor 1.875x is the price of killing the 67 MB
//   cm/cr round-trip + one launch.
// ---------------------------------------------------------------------------
__global__ __launch_bounds__(256, 1)
void fused_local_attn_kernel(const float* __restrict__ xm,
                             const float* __restrict__ xr,
                             const float* __restrict__ Wm,
                             const float* __restrict__ Wr,
                             float* __restrict__ out) {
    __shared__ float lds[16320];         // 65,280 B
    float* Wsh = lds;                    // [32][64]
    float* xsh = lds + 2048;             // [32][XSTRIDE]

    const int t   = threadIdx.x;
    const int tx0 = blockIdx.x * TILE_W;
    const int ty0 = blockIdx.y * TILE_H;
    const int b   = blockIdx.z;

    const int dg = t & 7;                // 8 d-groups of 8 output channels
    const int pg = t >> 3;               // 32 px-groups

    // ===================== phase 1: cm GEMM (128 px, 4px x 8d) ============
    float cmv[4][8];
    #pragma unroll
    for (int i = 0; i < 4; ++i)
        #pragma unroll
        for (int j = 0; j < 8; ++j) cmv[i][j] = 0.f;

    for (int kc = 0; kc < 2; ++kc) {
        {   // stage W_main chunk: 512 float4
            const float4* Wg4 = (const float4*)(Wm + kc * 32 * CDIM);
            ((float4*)Wsh)[t]       = Wg4[t];
            ((float4*)Wsh)[t + 256] = Wg4[t + 256];
        }
        // stage x_main^T chunk: 128 px x 8 f4 = 1024 f4, 4 iters
        #pragma unroll
        for (int i = 0; i < 4; ++i) {
            int L  = t + 256 * i;
            int px = L >> 3;                 // 0..127
            int c4 = L & 7;
            size_t gp = ((size_t)b * HDIM + ty0 + (px >> 4)) * WDIM
                        + tx0 + (px & 15);
            float4 v = *(const float4*)&xm[gp * CDIM + kc * 32 + 4 * c4];
            int ppx = px ^ (8 * (c4 & 3));
            xsh[(4 * c4 + 0) * XSTRIDE + ppx] = v.x;
            xsh[(4 * c4 + 1) * XSTRIDE + ppx] = v.y;
            xsh[(4 * c4 + 2) * XSTRIDE + ppx] = v.z;
            xsh[(4 * c4 + 3) * XSTRIDE + ppx] = v.w;
        }
        __syncthreads();
        #pragma unroll 4
        for (int c = 0; c < 32; ++c) {
            const int s = (c >> 2) & 3;
            float4 xv = *(const float4*)&xsh[c * XSTRIDE + ((4 * pg) ^ (8 * s))];
            const float4* wp = (const float4*)&Wsh[c * 64 + 8 * dg];
            float4 w0 = wp[0], w1 = wp[1];
            float xa[4] = {xv.x, xv.y, xv.z, xv.w};
            float wa[8] = {w0.x, w0.y, w0.z, w0.w, w1.x, w1.y, w1.z, w1.w};
            #pragma unroll
            for (int i = 0; i < 4; ++i)
                #pragma unroll
                for (int j = 0; j < 8; ++j)
                    cmv[i][j] = fmaf(xa[i], wa[j], cmv[i][j]);
        }
        __syncthreads();
    }

    // ===================== phase 2: cr GEMM (256 slots, 8px x 8d) =========
    float crv[8][8];
    #pragma unroll
    for (int i = 0; i < 8; ++i)
        #pragma unroll
        for (int j = 0; j < 8; ++j) crv[i][j] = 0.f;

    for (int kc = 0; kc < 2; ++kc) {
        {   // stage W_ref chunk
            const float4* Wg4 = (const float4*)(Wr + kc * 32 * CDIM);
            ((float4*)Wsh)[t]       = Wg4[t];
            ((float4*)Wsh)[t + 256] = Wg4[t + 256];
        }
        // stage x_ref^T halo chunk: 256 slots x 8 f4 = 2048 f4, 8 iters
        #pragma unroll
        for (int i = 0; i < 8; ++i) {
            int L    = t + 256 * i;
            int slot = L >> 3;               // 0..255
            int c4   = L & 7;
            float4 v = make_float4(0.f, 0.f, 0.f, 0.f);
            if (slot < NHALO) {
                int hy = slot / HALO_W;
                int hx = slot - hy * HALO_W;
                int gy = ty0 + hy - 2, gx = tx0 + hx - 2;
                if (gy >= 0 && gy < HDIM && gx >= 0 && gx < WDIM) {
                    size_t gp = ((size_t)b * HDIM + gy) * WDIM + gx;
                    v = *(const float4*)&xr[gp * CDIM + kc * 32 + 4 * c4];
                }
            }
            int ppx = slot ^ (8 * (c4 & 3));
            xsh[(4 * c4 + 0) * XSTRIDE + ppx] = v.x;
            xsh[(4 * c4 + 1) * XSTRIDE + ppx] = v.y;
            xsh[(4 * c4 + 2) * XSTRIDE + ppx] = v.z;
            xsh[(4 * c4 + 3) * XSTRIDE + ppx] = v.w;
        }
        __syncthreads();
        #pragma unroll 4
        for (int c = 0; c < 32; ++c) {
            const int s = (c >> 2) & 3;
            const float4* xp = (const float4*)&xsh[c * XSTRIDE + ((8 * pg) ^ (8 * s))];
            const float4* wp = (const float4*)&Wsh[c * 64 + 8 * dg];
            float4 x0 = xp[0], x1 = xp[1];
            float4 w0 = wp[0], w1 = wp[1];
            float xa[8] = {x0.x, x0.y, x0.z, x0.w, x1.x, x1.y, x1.z, x1.w};
            float wa[8] = {w0.x, w0.y, w0.z, w0.w, w1.x, w1.y, w1.z, w1.w};
            #pragma unroll
            for (int i = 0; i < 8; ++i)
                #pragma unroll
                for (int j = 0; j < 8; ++j)
                    crv[i][j] = fmaf(xa[i], wa[j], crv[i][j]);
        }
        __syncthreads();
    }

    // ===================== phase 3: cm -> LDS, extract qv =================
    #pragma unroll
    for (int i = 0; i < 4; ++i) {
        int px = 4 * pg + i;
        float4 o0 = {cmv[i][0], cmv[i][1], cmv[i][2], cmv[i][3]};
        float4 o1 = {cmv[i][4], cmv[i][5], cmv[i][6], cmv[i][7]};
        *(float4*)&lds[px * PSTRIDE + 8 * dg]     = o0;
        *(float4*)&lds[px * PSTRIDE + 8 * dg + 4] = o1;
    }
    __syncthreads();

    const int pl = t >> 1;               // local pixel 0..127
    const int cg = t & 1;                // channel half
    float4 qv[8];
    #pragma unroll
    for (int m = 0; m < 8; ++m)
        qv[m] = *(const float4*)&lds[pl * PSTRIDE + cg * 32 + 4 * m];
    __syncthreads();                     // qv safe in regs before overwrite

    // ===================== phase 4: cr -> crs =============================
    #pragma unroll
    for (int i = 0; i < 8; ++i) {
        int slot = 8 * pg + i;
        if (slot < NHALO) {
            float4 o0 = {crv[i][0], crv[i][1], crv[i][2], crv[i][3]};
            float4 o1 = {crv[i][4], crv[i][5], crv[i][6], crv[i][7]};
            *(float4*)&lds[slot * PSTRIDE + 8 * dg]     = o0;
            *(float4*)&lds[slot * PSTRIDE + 8 * dg + 4] = o1;
        }
    }
    __syncthreads();

    // ===================== phase 5: scores + softmax (v4) =================
    const int lx = pl & (TILE_W - 1);
    const int ly = pl >> 4;
    const size_t gpx = ((size_t)b * HDIM + ty0 + ly) * WDIM + tx0 + lx;

    float s[26];
    #pragma unroll
    for (int k = 0; k < 25; ++k) {
        const int i = k / 5, j = k % 5;
        const int p = (ly + i) * HALO_W + (lx + j);
        const float4* kp = (const float4*)&lds[p * PSTRIDE + cg * 32];
        float acc = 0.f;
        #pragma unroll
        for (int m = 0; m < 8; ++m) {
            float4 v = kp[m];
            acc = fmaf(qv[m].x, v.x, acc);
            acc = fmaf(qv[m].y, v.y, acc);
            acc = fmaf(qv[m].z, v.z, acc);
            acc = fmaf(qv[m].w, v.w, acc);
        }
        s[k] = acc;
    }
    {
        float acc = 0.f;
        #pragma unroll
        for (int m = 0; m < 8; ++m) {
            float4 v = qv[m];
            acc = fmaf(v.x, v.x, acc);
            acc = fmaf(v.y, v.y, acc);
            acc = fmaf(v.z, v.z, acc);
            acc = fmaf(v.w, v.w, acc);
        }
        s[25] = acc;
    }

    #pragma unroll
    for (int k = 0; k < 26; ++k) s[k] += __shfl_xor(s[k], 1);

    float mx = s[0];
    #pragma unroll
    for (int k = 1; k < 26; ++k) mx = fmaxf(mx, s[k]);
    float sum = 0.f;
    #pragma unroll
    for (int k = 0; k < 26; ++k) { s[k] = __expf(s[k] - mx); sum += s[k]; }
    const float inv = 1.f / sum;

    // all indices compile-time -> s[] stays in VGPRs
    float* op = &out[gpx * 26 + cg * 13];
    if (cg == 0) {
        #pragma unroll
        for (int k = 0; k < 13; ++k) op[k] = s[k] * inv;
    } else {
        #pragma unroll
        for (int k = 0; k < 13; ++k) op[k] = s[13 + k] * inv;
    }
}

// ---------------------------------------------------------------------------
extern "C" void kernel_launch(void* const* d_in, const int* in_sizes, int n_in,
                              void* d_out, int out_size, void* d_ws, size_t ws_size,
                              hipStream_t stream) {
    const float* xm = (const float*)d_in[0];
    const float* xr = (const float*)d_in[1];
    const float* Wm = (const float*)d_in[2];
    const float* Wr = (const float*)d_in[3];
    float* outp = (float*)d_out;

    dim3 g(WDIM / TILE_W, HDIM / TILE_H, BDIM);   // 8 x 16 x 4 = 512 blocks
    fused_local_attn_kernel<<<g, 256, 0, stream>>>(xm, xr, Wm, Wr, outp);
}

// Round 8
// 99.069 us; speedup vs baseline: 1.1470x; 1.0387x over previous
//
#include <hip/hip_runtime.h>
#include <math.h>

#define HDIM 128
#define WDIM 128
#define CDIM 64
#define BDIM 4
#define NPIX (BDIM * HDIM * WDIM)   // 65536

typedef short bf16x8 __attribute__((ext_vector_type(8)));  // 8 bf16 (4 VGPRs)
typedef float f32x4  __attribute__((ext_vector_type(4)));  // MFMA accumulator

// exact fp32 -> bf16 hi/lo split: f = hi + lo with |err(products)| ~ 2^-14
__device__ __forceinline__ void split_bf16(float f, short& hi, short& lo) {
    unsigned u = __float_as_uint(f);
    hi = (short)(u >> 16);                       // truncated bf16 (hi)
    float hf = __uint_as_float(u & 0xffff0000u); // exact hi as f32
    float l  = f - hf;                           // exact remainder (Sterbenz)
    lo = (short)(__float_as_uint(l) >> 16);
}

// ---------------------------------------------------------------------------
// Kernel 1 (v4): dual 1x1 conv via split-bf16 MFMA (3-product emulated fp32).
//   GEMM [65536 x 64] @ [64 x 64] per input. Per wave: 4 M-tiles of 16 px.
//   A-frags (A[m=lane&15][k=quad*8+j], m120-verified) come STRAIGHT from
//   global — no LDS staging/transpose (kills the old 4-b128-per-64-FMA LDS
//   tax that pinned VALU conv at ~28 us). W staged to LDS once; all 16
//   B-frags (2 Kstep x 4 Ntile x hi/lo) built once into 64 VGPRs.
//   C/D: row=(lane>>4)*4+reg, col=lane&15 (m89-verified) -> dword stores in
//   64-B coalesced runs. Expect HBM-bound: 67 MB r+w ~ 11-13 us.
// ---------------------------------------------------------------------------
__global__ __launch_bounds__(256, 1)
void conv1x1_mfma_kernel(const float* __restrict__ xm,
                         const float* __restrict__ xr,
                         const float* __restrict__ Wm,
                         const float* __restrict__ Wr,
                         float* __restrict__ outm,
                         float* __restrict__ outr) {
    const float* x; const float* Wg; float* out;
    if (blockIdx.y == 0) { x = xm; Wg = Wm; out = outm; }
    else                 { x = xr; Wg = Wr; out = outr; }

    __shared__ float Wsh[CDIM * CDIM];   // 16 KB
    const int t = threadIdx.x;
    {
        const float4* Wg4 = (const float4*)Wg;
        float4* Ws4 = (float4*)Wsh;
        #pragma unroll
        for (int i = 0; i < 4; ++i) Ws4[t + 256 * i] = Wg4[t + 256 * i];
    }
    __syncthreads();

    const int lane = t & 63;
    const int wv   = t >> 6;             // wave 0..3
    const int m    = lane & 15;          // A row / B col / D col
    const int quad = lane >> 4;          // k-group (A/B), row-group (D)

    // ---- build all B fragments from LDS (once) ----
    bf16x8 Bhi[2][4], Blo[2][4];
    #pragma unroll
    for (int ks = 0; ks < 2; ++ks) {
        #pragma unroll
        for (int nt = 0; nt < 4; ++nt) {
            #pragma unroll
            for (int j = 0; j < 8; ++j) {
                float f = Wsh[(ks * 32 + quad * 8 + j) * CDIM + nt * 16 + m];
                short hi, lo; split_bf16(f, hi, lo);
                Bhi[ks][nt][j] = hi;
                Blo[ks][nt][j] = lo;
            }
        }
    }

    // ---- 4 M-tiles (16 px each) per wave; A prefetched up-front ----
    const int tbase = (blockIdx.x * 4 + wv) * 4;   // tile index base

    float4 pa[4][4];
    #pragma unroll
    for (int it = 0; it < 4; ++it) {
        const float* ap = x + ((size_t)((tbase + it) * 16 + m)) * CDIM + quad * 8;
        pa[it][0] = *(const float4*)(ap);        // kstep0, j 0..3
        pa[it][1] = *(const float4*)(ap + 4);    // kstep0, j 4..7
        pa[it][2] = *(const float4*)(ap + 32);   // kstep1, j 0..3
        pa[it][3] = *(const float4*)(ap + 36);   // kstep1, j 4..7
    }

    #pragma unroll
    for (int it = 0; it < 4; ++it) {
        bf16x8 Ahi[2], Alo[2];
        #pragma unroll
        for (int ks = 0; ks < 2; ++ks) {
            float fv[8];
            float4 p = pa[it][2 * ks], q = pa[it][2 * ks + 1];
            fv[0] = p.x; fv[1] = p.y; fv[2] = p.z; fv[3] = p.w;
            fv[4] = q.x; fv[5] = q.y; fv[6] = q.z; fv[7] = q.w;
            #pragma unroll
            for (int j = 0; j < 8; ++j) {
                short hi, lo; split_bf16(fv[j], hi, lo);
                Ahi[ks][j] = hi;
                Alo[ks][j] = lo;
            }
        }

        f32x4 acc[4];
        #pragma unroll
        for (int nt = 0; nt < 4; ++nt) {
            acc[nt][0] = 0.f; acc[nt][1] = 0.f;
            acc[nt][2] = 0.f; acc[nt][3] = 0.f;
        }
        #pragma unroll
        for (int ks = 0; ks < 2; ++ks) {
            #pragma unroll
            for (int nt = 0; nt < 4; ++nt) {
                acc[nt] = __builtin_amdgcn_mfma_f32_16x16x32_bf16(
                              Ahi[ks], Bhi[ks][nt], acc[nt], 0, 0, 0);
                acc[nt] = __builtin_amdgcn_mfma_f32_16x16x32_bf16(
                              Ahi[ks], Blo[ks][nt], acc[nt], 0, 0, 0);
                acc[nt] = __builtin_amdgcn_mfma_f32_16x16x32_bf16(
                              Alo[ks], Bhi[ks][nt], acc[nt], 0, 0, 0);
            }
        }

        // D[row = quad*4 + r][col = nt*16 + m]
        float* op = out + ((size_t)((tbase + it) * 16 + quad * 4)) * CDIM + m;
        #pragma unroll
        for (int nt = 0; nt < 4; ++nt) {
            #pragma unroll
            for (int r = 0; r < 4; ++r)
                op[(size_t)r * CDIM + nt * 16] = acc[nt][r];
        }
    }
}

// ---------------------------------------------------------------------------
// Kernel 2 (v4, unchanged & proven): LDS-tiled scores + softmax.
// ---------------------------------------------------------------------------
#define TILE_W 16
#define TILE_H 8
#define HALO_W 20
#define HALO_H 12
#define NHALO (HALO_W * HALO_H) // 240
#define PSTRIDE 68

__global__ __launch_bounds__(256, 1)
void attn_tiled_kernel(const float* __restrict__ cm,
                       const float* __restrict__ cr,
                       float* __restrict__ out) {
    __shared__ float crs[NHALO * PSTRIDE];   // 65,280 B

    const int t   = threadIdx.x;
    const int tx0 = blockIdx.x * TILE_W;
    const int ty0 = blockIdx.y * TILE_H;
    const int b   = blockIdx.z;

    #pragma unroll
    for (int it = 0; it < 15; ++it) {
        int L   = t + 256 * it;
        int pix = L >> 4;
        int q   = L & 15;
        int hy  = pix / HALO_W;
        int hx  = pix - hy * HALO_W;
        int gy  = ty0 + hy - 2, gx = tx0 + hx - 2;
        float4 v = make_float4(0.f, 0.f, 0.f, 0.f);
        if (gy >= 0 && gy < HDIM && gx >= 0 && gx < WDIM) {
            size_t gp = ((size_t)b * HDIM + gy) * WDIM + gx;
            v = *(const float4*)&cr[gp * CDIM + 4 * q];
        }
        *(float4*)&crs[pix * PSTRIDE + 4 * q] = v;
    }
    __syncthreads();

    const int pl = t >> 1;
    const int cg = t & 1;
    const int lx = pl & (TILE_W - 1);
    const int ly = pl >> 4;
    const size_t gpx = ((size_t)b * HDIM + ty0 + ly) * WDIM + tx0 + lx;

    float4 qv[8];
    {
        const float4* cmp = (const float4*)&cm[gpx * CDIM + cg * 32];
        #pragma unroll
        for (int mq = 0; mq < 8; ++mq) qv[mq] = cmp[mq];
    }

    float s[26];
    #pragma unroll
    for (int k = 0; k < 25; ++k) {
        const int i = k / 5, j = k % 5;
        const int p = (ly + i) * HALO_W + (lx + j);
        const float4* kp = (const float4*)&crs[p * PSTRIDE + cg * 32];
        float acc = 0.f;
        #pragma unroll
        for (int mq = 0; mq < 8; ++mq) {
            float4 v = kp[mq];
            acc = fmaf(qv[mq].x, v.x, acc);
            acc = fmaf(qv[mq].y, v.y, acc);
            acc = fmaf(qv[mq].z, v.z, acc);
            acc = fmaf(qv[mq].w, v.w, acc);
        }
        s[k] = acc;
    }
    {
        float acc = 0.f;
        #pragma unroll
        for (int mq = 0; mq < 8; ++mq) {
            float4 v = qv[mq];
            acc = fmaf(v.x, v.x, acc);
            acc = fmaf(v.y, v.y, acc);
            acc = fmaf(v.z, v.z, acc);
            acc = fmaf(v.w, v.w, acc);
        }
        s[25] = acc;
    }

    #pragma unroll
    for (int k = 0; k < 26; ++k) s[k] += __shfl_xor(s[k], 1);

    float mx = s[0];
    #pragma unroll
    for (int k = 1; k < 26; ++k) mx = fmaxf(mx, s[k]);
    float sum = 0.f;
    #pragma unroll
    for (int k = 0; k < 26; ++k) { s[k] = __expf(s[k] - mx); sum += s[k]; }
    const float inv = 1.f / sum;

    float* op = &out[gpx * 26 + cg * 13];
    if (cg == 0) {
        #pragma unroll
        for (int k = 0; k < 13; ++k) op[k] = s[k] * inv;
    } else {
        #pragma unroll
        for (int k = 0; k < 13; ++k) op[k] = s[13 + k] * inv;
    }
}

// ---------------------------------------------------------------------------
extern "C" void kernel_launch(void* const* d_in, const int* in_sizes, int n_in,
                              void* d_out, int out_size, void* d_ws, size_t ws_size,
                              hipStream_t stream) {
    const float* xm = (const float*)d_in[0];
    const float* xr = (const float*)d_in[1];
    const float* Wm = (const float*)d_in[2];
    const float* Wr = (const float*)d_in[3];
    float* outp = (float*)d_out;

    float* cm = (float*)d_ws;                  // NPIX*64 floats
    float* cr = cm + (size_t)NPIX * CDIM;      // NPIX*64 floats

    // 256 blocks x 4 waves x 4 tiles x 16 px = 65536 px, x2 inputs
    dim3 g1(256, 2);
    conv1x1_mfma_kernel<<<g1, 256, 0, stream>>>(xm, xr, Wm, Wr, cm, cr);

    dim3 g2(WDIM / TILE_W, HDIM / TILE_H, BDIM);   // 8 x 16 x 4 = 512 blocks
    attn_tiled_kernel<<<g2, 256, 0, stream>>>(cm, cr, outp);
}

// Round 9
// 89.997 us; speedup vs baseline: 1.2626x; 1.1008x over previous
//
#include <hip/hip_runtime.h>
#include <math.h>

#define HDIM 128
#define WDIM 128
#define CDIM 64
#define BDIM 4

#define TILE_W 16
#define TILE_H 8
#define HALO_W 20
#define HALO_H 12
#define NHALO (HALO_W * HALO_H)   // 240 halo px = 15 M-tiles of 16
#define PSTRIDE 68                // cm/crs pixel stride (16B-aligned, 4 mod 32)
#define WSTRIDE 65                // W LDS stride (k*65+d: 2-way banks on frag reads)

typedef short bf16x8 __attribute__((ext_vector_type(8)));
typedef float f32x4  __attribute__((ext_vector_type(4)));

// exact fp32 -> bf16 hi/lo split (3-product emulation, |err| ~ 2^-14)
__device__ __forceinline__ void split_bf16(float f, short& hi, short& lo) {
    unsigned u = __float_as_uint(f);
    hi = (short)(u >> 16);
    float hf = __uint_as_float(u & 0xffff0000u);
    float l  = f - hf;
    lo = (short)(__float_as_uint(l) >> 16);
}

// ---------------------------------------------------------------------------
// Fully fused: split-bf16 MFMA convs (cm + cr halo) + scores + softmax.
//   LDS (65,280 B) time-multiplexed:
//     Wsh [0..4160)        W[k][d] stride 65 (Wm then Wr, restaged)
//     cms [4352..13056)    cm[128 px][68]
//     crs [0..16320)       crs[240 px][68]   (phase 5+, overwrites all)
//   A-frags straight from global (round-8-proven layout: A[m=lane&15]
//   [k=quad*8+j], D row=quad*4+reg col=lane&15). No ws round-trip.
//   cr halo recompute 1.875x ~ 1 us of MFMA — cheap vs 67 MB of HBM.
// ---------------------------------------------------------------------------
__global__ __launch_bounds__(256, 1)
void fused_mfma_local_attn(const float* __restrict__ xm,
                           const float* __restrict__ xr,
                           const float* __restrict__ Wm,
                           const float* __restrict__ Wr,
                           float* __restrict__ out) {
    __shared__ float lds[16320];        // 65,280 B
    float* Wsh = lds;                   // [64][65]
    float* cms = lds + 4352;            // [128][68]
    float* crs = lds;                   // [240][68]

    const int t    = threadIdx.x;
    const int lane = t & 63;
    const int wv   = t >> 6;            // wave 0..3
    const int m    = lane & 15;
    const int quad = lane >> 4;
    const int tx0  = blockIdx.x * TILE_W;
    const int ty0  = blockIdx.y * TILE_H;
    const int b    = blockIdx.z;

    // ============ phase 1: stage Wm (scalar, stride 65) ============
    #pragma unroll
    for (int i = 0; i < 16; ++i) {
        int L = t + 256 * i;            // wave-aligned: k = L>>6 uniform/wave
        Wsh[(L >> 6) * WSTRIDE + (L & 63)] = Wm[L];
    }
    __syncthreads();

    // build Bm frags: B[k=ks*32+quad*8+j][n=nt*16+m]
    bf16x8 Bhi[2][4], Blo[2][4];
    #pragma unroll
    for (int ks = 0; ks < 2; ++ks)
        #pragma unroll
        for (int nt = 0; nt < 4; ++nt)
            #pragma unroll
            for (int j = 0; j < 8; ++j) {
                float f = Wsh[(ks * 32 + quad * 8 + j) * WSTRIDE + nt * 16 + m];
                short hi, lo; split_bf16(f, hi, lo);
                Bhi[ks][nt][j] = hi; Blo[ks][nt][j] = lo;
            }

    // ============ phase 2: cm GEMM — 2 M-tiles (rows) per wave ============
    #pragma unroll
    for (int s = 0; s < 2; ++s) {
        const int tile = 2 * wv + s;                 // row ty0+tile
        const float* ap = xm + (((size_t)b * HDIM + ty0 + tile) * WDIM
                                + tx0 + m) * CDIM + quad * 8;
        float4 p0 = *(const float4*)(ap);
        float4 p1 = *(const float4*)(ap + 4);
        float4 p2 = *(const float4*)(ap + 32);
        float4 p3 = *(const float4*)(ap + 36);

        bf16x8 Ahi[2], Alo[2];
        {
            float fv[16] = {p0.x,p0.y,p0.z,p0.w, p1.x,p1.y,p1.z,p1.w,
                            p2.x,p2.y,p2.z,p2.w, p3.x,p3.y,p3.z,p3.w};
            #pragma unroll
            for (int ks = 0; ks < 2; ++ks)
                #pragma unroll
                for (int j = 0; j < 8; ++j) {
                    short hi, lo; split_bf16(fv[8 * ks + j], hi, lo);
                    Ahi[ks][j] = hi; Alo[ks][j] = lo;
                }
        }
        f32x4 acc[4];
        #pragma unroll
        for (int nt = 0; nt < 4; ++nt)
            { acc[nt][0]=0.f; acc[nt][1]=0.f; acc[nt][2]=0.f; acc[nt][3]=0.f; }
        #pragma unroll
        for (int ks = 0; ks < 2; ++ks)
            #pragma unroll
            for (int nt = 0; nt < 4; ++nt) {
                acc[nt] = __builtin_amdgcn_mfma_f32_16x16x32_bf16(Ahi[ks], Bhi[ks][nt], acc[nt], 0,0,0);
                acc[nt] = __builtin_amdgcn_mfma_f32_16x16x32_bf16(Ahi[ks], Blo[ks][nt], acc[nt], 0,0,0);
                acc[nt] = __builtin_amdgcn_mfma_f32_16x16x32_bf16(Alo[ks], Bhi[ks][nt], acc[nt], 0,0,0);
            }
        // D: pixel-in-tile = quad*4+r, channel = nt*16+m
        #pragma unroll
        for (int nt = 0; nt < 4; ++nt)
            #pragma unroll
            for (int r = 0; r < 4; ++r)
                cms[(tile * 16 + quad * 4 + r) * PSTRIDE + nt * 16 + m] = acc[nt][r];
    }
    __syncthreads();   // Bm W-reads done + cms visible

    // ============ phase 3: restage Wr, Br frags, qv extract ============
    #pragma unroll
    for (int i = 0; i < 16; ++i) {
        int L = t + 256 * i;
        Wsh[(L >> 6) * WSTRIDE + (L & 63)] = Wr[L];
    }
    __syncthreads();

    #pragma unroll
    for (int ks = 0; ks < 2; ++ks)
        #pragma unroll
        for (int nt = 0; nt < 4; ++nt)
            #pragma unroll
            for (int j = 0; j < 8; ++j) {
                float f = Wsh[(ks * 32 + quad * 8 + j) * WSTRIDE + nt * 16 + m];
                short hi, lo; split_bf16(f, hi, lo);
                Bhi[ks][nt][j] = hi; Blo[ks][nt][j] = lo;
            }

    const int pl = t >> 1;              // local pixel 0..127
    const int cg = t & 1;               // channel half
    float4 qv[8];
    #pragma unroll
    for (int mq = 0; mq < 8; ++mq)
        qv[mq] = *(const float4*)&cms[pl * PSTRIDE + cg * 32 + 4 * mq];
    __syncthreads();   // Wr reads + cms reads done before crs overwrites

    // ============ phase 4: cr halo GEMM — 15 M-tiles over 4 waves ============
    #pragma unroll
    for (int s = 0; s < 4; ++s) {
        const int tj = wv + 4 * s;
        if (tj < 15) {
            // A row = halo px tj*16 + m
            const int hp = tj * 16 + m;
            const int hy = hp / HALO_W;
            const int hx = hp - hy * HALO_W;
            const int gy = ty0 + hy - 2, gx = tx0 + hx - 2;
            float4 p0 = make_float4(0,0,0,0), p1 = p0, p2 = p0, p3 = p0;
            if (gy >= 0 && gy < HDIM && gx >= 0 && gx < WDIM) {
                const float* ap = xr + (((size_t)b * HDIM + gy) * WDIM + gx) * CDIM
                                  + quad * 8;
                p0 = *(const float4*)(ap);
                p1 = *(const float4*)(ap + 4);
                p2 = *(const float4*)(ap + 32);
                p3 = *(const float4*)(ap + 36);
            }
            bf16x8 Ahi[2], Alo[2];
            {
                float fv[16] = {p0.x,p0.y,p0.z,p0.w, p1.x,p1.y,p1.z,p1.w,
                                p2.x,p2.y,p2.z,p2.w, p3.x,p3.y,p3.z,p3.w};
                #pragma unroll
                for (int ks = 0; ks < 2; ++ks)
                    #pragma unroll
                    for (int j = 0; j < 8; ++j) {
                        short hi, lo; split_bf16(fv[8 * ks + j], hi, lo);
                        Ahi[ks][j] = hi; Alo[ks][j] = lo;
                    }
            }
            f32x4 acc[4];
            #pragma unroll
            for (int nt = 0; nt < 4; ++nt)
                { acc[nt][0]=0.f; acc[nt][1]=0.f; acc[nt][2]=0.f; acc[nt][3]=0.f; }
            #pragma unroll
            for (int ks = 0; ks < 2; ++ks)
                #pragma unroll
                for (int nt = 0; nt < 4; ++nt) {
                    acc[nt] = __builtin_amdgcn_mfma_f32_16x16x32_bf16(Ahi[ks], Bhi[ks][nt], acc[nt], 0,0,0);
                    acc[nt] = __builtin_amdgcn_mfma_f32_16x16x32_bf16(Ahi[ks], Blo[ks][nt], acc[nt], 0,0,0);
                    acc[nt] = __builtin_amdgcn_mfma_f32_16x16x32_bf16(Alo[ks], Bhi[ks][nt], acc[nt], 0,0,0);
                }
            #pragma unroll
            for (int nt = 0; nt < 4; ++nt)
                #pragma unroll
                for (int r = 0; r < 4; ++r)
                    crs[(tj * 16 + quad * 4 + r) * PSTRIDE + nt * 16 + m] = acc[nt][r];
        }
    }
    __syncthreads();

    // ============ phase 5: scores + softmax (v4, proven) ============
    const int lx = pl & (TILE_W - 1);
    const int ly = pl >> 4;
    const size_t gpx = ((size_t)b * HDIM + ty0 + ly) * WDIM + tx0 + lx;

    float s[26];
    #pragma unroll
    for (int k = 0; k < 25; ++k) {
        const int i = k / 5, j = k % 5;
        const int p = (ly + i) * HALO_W + (lx + j);
        const float4* kp = (const float4*)&crs[p * PSTRIDE + cg * 32];
        float acc = 0.f;
        #pragma unroll
        for (int mq = 0; mq < 8; ++mq) {
            float4 v = kp[mq];
            acc = fmaf(qv[mq].x, v.x, acc);
            acc = fmaf(qv[mq].y, v.y, acc);
            acc = fmaf(qv[mq].z, v.z, acc);
            acc = fmaf(qv[mq].w, v.w, acc);
        }
        s[k] = acc;
    }
    {
        float acc = 0.f;
        #pragma unroll
        for (int mq = 0; mq < 8; ++mq) {
            float4 v = qv[mq];
            acc = fmaf(v.x, v.x, acc);
            acc = fmaf(v.y, v.y, acc);
            acc = fmaf(v.z, v.z, acc);
            acc = fmaf(v.w, v.w, acc);
        }
        s[25] = acc;
    }

    #pragma unroll
    for (int k = 0; k < 26; ++k) s[k] += __shfl_xor(s[k], 1);

    float mx = s[0];
    #pragma unroll
    for (int k = 1; k < 26; ++k) mx = fmaxf(mx, s[k]);
    float sum = 0.f;
    #pragma unroll
    for (int k = 0; k < 26; ++k) { s[k] = __expf(s[k] - mx); sum += s[k]; }
    const float inv = 1.f / sum;

    float* op = &out[gpx * 26 + cg * 13];
    if (cg == 0) {
        #pragma unroll
        for (int k = 0; k < 13; ++k) op[k] = s[k] * inv;
    } else {
        #pragma unroll
        for (int k = 0; k < 13; ++k) op[k] = s[13 + k] * inv;
    }
}

// ---------------------------------------------------------------------------
extern "C" void kernel_launch(void* const* d_in, const int* in_sizes, int n_in,
                              void* d_out, int out_size, void* d_ws, size_t ws_size,
                              hipStream_t stream) {
    const float* xm = (const float*)d_in[0];
    const float* xr = (const float*)d_in[1];
    const float* Wm = (const float*)d_in[2];
    const float* Wr = (const float*)d_in[3];
    float* outp = (float*)d_out;

    dim3 g(WDIM / TILE_W, HDIM / TILE_H, BDIM);   // 8 x 16 x 4 = 512 blocks
    fused_mfma_local_attn<<<g, 256, 0, stream>>>(xm, xr, Wm, Wr, outp);
}